// Round 1
// baseline (491.590 us; speedup 1.0000x reference)
//
#include <hip/hip_runtime.h>

// EncoderBlock: B=2, S=2048, D=1024, H=16, HD=64, F=4096, M=B*S=4096 tokens.
// All GEMMs are X[M,K] @ W[N,K]^T -> bf16 MFMA 16x16x32, m97-style structure:
// 128x128 tile, BK=32, 4 waves each 64x64, global_load_lds width-16 staging.

typedef unsigned short u16;
typedef unsigned int u32;
typedef __attribute__((ext_vector_type(8))) __bf16 bf16x8;
typedef __attribute__((ext_vector_type(4))) float f32x4;

__device__ __forceinline__ u16 f2bf(float f) {
  u32 u = __float_as_uint(f);
  u += 0x7fffu + ((u >> 16) & 1u);   // RNE
  return (u16)(u >> 16);
}

__device__ __forceinline__ void async16(const void* g, void* l) {
  __builtin_amdgcn_global_load_lds((__attribute__((address_space(1))) void*)g,
                                   (__attribute__((address_space(3))) void*)l,
                                   16, 0, 0);
}

__device__ __forceinline__ f32x4 mfma16(bf16x8 a, bf16x8 b, f32x4 c) {
  return __builtin_amdgcn_mfma_f32_16x16x32_bf16(a, b, c, 0, 0, 0);
}

// ---------------- fp32 -> bf16 convert (4 elems/thread) ----------------
__global__ __launch_bounds__(256) void cvt_bf16(const float* __restrict__ in,
                                                u16* __restrict__ out) {
  int i = blockIdx.x * 256 + threadIdx.x;
  float4 v = ((const float4*)in)[i];
  ushort4 o;
  o.x = f2bf(v.x); o.y = f2bf(v.y); o.z = f2bf(v.z); o.w = f2bf(v.w);
  ((ushort4*)out)[i] = o;
}

// ---------------- GEMM: C[M,N] = A[M,K] @ W[N,K]^T + bias ----------------
// MODE 0: fp32 out. MODE 1: bf16 out with ReLU. MODE 2: QKV scatter
// (q scaled by 1/8, v stored transposed [B,H,64,S]).
template <int MODE>
__global__ __launch_bounds__(256)
void gemm_bt(const u16* __restrict__ A, const u16* __restrict__ W,
             const float* __restrict__ bias,
             float* __restrict__ outf, u16* __restrict__ outb,
             u16* __restrict__ qo, u16* __restrict__ ko, u16* __restrict__ vto,
             int M, int N, int K) {
  __shared__ u16 As[128 * 32];
  __shared__ u16 Bs[128 * 32];
  const int lane = threadIdx.x & 63;
  const int wave = threadIdx.x >> 6;
  const int lrow = lane & 15;
  const int lquad = lane >> 4;
  const int tm = blockIdx.x * 128;
  const int tn = blockIdx.y * 128;
  const int wm = (wave >> 1) * 64;
  const int wn = (wave & 1) * 64;
  f32x4 acc[4][4] = {};

  for (int k0 = 0; k0 < K; k0 += 32) {
#pragma unroll
    for (int c = 0; c < 2; ++c) {
      int chunk = wave * 128 + c * 64 + lane;   // 512 16B chunks per tile
      int row = chunk >> 2;
      int kc = (chunk & 3) << 3;
      u16* la = As + (size_t)(wave * 128 + c * 64) * 8;  // wave-uniform base
      u16* lb = Bs + (size_t)(wave * 128 + c * 64) * 8;
      async16(A + (size_t)(tm + row) * K + (k0 + kc), la);
      async16(W + (size_t)(tn + row) * K + (k0 + kc), lb);
    }
    __syncthreads();
    bf16x8 a_frag[4], b_frag[4];
#pragma unroll
    for (int i = 0; i < 4; ++i)
      a_frag[i] = *(const bf16x8*)(As + (wm + i * 16 + lrow) * 32 + lquad * 8);
#pragma unroll
    for (int j = 0; j < 4; ++j)
      b_frag[j] = *(const bf16x8*)(Bs + (wn + j * 16 + lrow) * 32 + lquad * 8);
#pragma unroll
    for (int i = 0; i < 4; ++i)
#pragma unroll
      for (int j = 0; j < 4; ++j)
        acc[i][j] = mfma16(a_frag[i], b_frag[j], acc[i][j]);
    __syncthreads();
  }

#pragma unroll
  for (int i = 0; i < 4; ++i) {
#pragma unroll
    for (int j = 0; j < 4; ++j) {
      int col = tn + wn + j * 16 + lrow;
      float bv = bias[col];
#pragma unroll
      for (int r = 0; r < 4; ++r) {
        int row = tm + wm + i * 16 + lquad * 4 + r;
        float v = acc[i][j][r] + bv;
        if constexpr (MODE == 0) {
          outf[(size_t)row * N + col] = v;
        } else if constexpr (MODE == 1) {
          outb[(size_t)row * N + col] = f2bf(fmaxf(v, 0.f));
        } else {
          int b = row >> 11, s = row & 2047;
          int h = col / 192, c = col - h * 192;
          size_t tok = (size_t)(b * 16 + h) * 2048 + s;
          if (c < 64)
            qo[tok * 64 + c] = f2bf(v * 0.125f);        // fold 1/sqrt(64)
          else if (c < 128)
            ko[tok * 64 + (c - 64)] = f2bf(v);
          else
            vto[((size_t)(b * 16 + h) * 64 + (c - 128)) * 2048 + s] = f2bf(v);
        }
      }
    }
  }
}

// ---------------- Flash attention ----------------
// grid (S/128, B*H); 4 waves, each owns 32 q rows. K/V tiles of 128 keys.
// Q pre-scaled by 1/8. V stored transposed [B,H,64,S].
__global__ __launch_bounds__(256)
void attn_kernel(const u16* __restrict__ Q, const u16* __restrict__ K,
                 const u16* __restrict__ Vt, u16* __restrict__ ctx) {
  __shared__ u16 Ks[128 * 64];
  __shared__ u16 Vs[64 * 128];
  __shared__ u16 Ps[128 * 128];
  const int lane = threadIdx.x & 63;
  const int wave = threadIdx.x >> 6;
  const int lrow = lane & 15;
  const int lquad = lane >> 4;
  const int qb = blockIdx.x;
  const int bh = blockIdx.y;
  const u16* Qp = Q + ((size_t)bh * 2048 + qb * 128) * 64;
  const u16* Kp = K + (size_t)bh * 2048 * 64;
  const u16* Vp = Vt + (size_t)bh * 64 * 2048;

  bf16x8 qf[2][2];
#pragma unroll
  for (int i = 0; i < 2; ++i)
#pragma unroll
    for (int kk = 0; kk < 2; ++kk)
      qf[i][kk] = *(const bf16x8*)(Qp + (wave * 32 + i * 16 + lrow) * 64 +
                                   kk * 32 + lquad * 8);

  f32x4 oacc[2][4] = {};
  float mrow[2][4], lsum[2][4];
#pragma unroll
  for (int i = 0; i < 2; ++i)
#pragma unroll
    for (int r = 0; r < 4; ++r) { mrow[i][r] = -1e30f; lsum[i][r] = 0.f; }

  for (int kb = 0; kb < 16; ++kb) {
    // stage K tile [128 keys][64 hd]: 1024 chunks
#pragma unroll
    for (int c = 0; c < 4; ++c) {
      int chunk = wave * 256 + c * 64 + lane;
      int row = chunk >> 3, cc = chunk & 7;
      async16(Kp + (size_t)(kb * 128 + row) * 64 + cc * 8,
              Ks + (size_t)(wave * 256 + c * 64) * 8);
    }
    // stage Vt tile [64 hd][128 keys]
#pragma unroll
    for (int c = 0; c < 4; ++c) {
      int chunk = wave * 256 + c * 64 + lane;
      int row = chunk >> 4, cc = chunk & 15;
      async16(Vp + (size_t)row * 2048 + kb * 128 + cc * 8,
              Vs + (size_t)(wave * 256 + c * 64) * 8);
    }
    __syncthreads();

    // S = Q @ K^T : 32 q rows x 128 keys per wave
    f32x4 sacc[2][8] = {};
#pragma unroll
    for (int j = 0; j < 8; ++j)
#pragma unroll
      for (int kk = 0; kk < 2; ++kk) {
        bf16x8 kf = *(const bf16x8*)(Ks + (j * 16 + lrow) * 64 + kk * 32 + lquad * 8);
        sacc[0][j] = mfma16(qf[0][kk], kf, sacc[0][j]);
        sacc[1][j] = mfma16(qf[1][kk], kf, sacc[1][j]);
      }

    // online softmax (row stats shared across the 16 col-lanes)
    float alpha[2][4];
#pragma unroll
    for (int i = 0; i < 2; ++i)
#pragma unroll
      for (int r = 0; r < 4; ++r) {
        float rm = sacc[i][0][r];
#pragma unroll
        for (int j = 1; j < 8; ++j) rm = fmaxf(rm, sacc[i][j][r]);
        rm = fmaxf(rm, __shfl_xor(rm, 1));
        rm = fmaxf(rm, __shfl_xor(rm, 2));
        rm = fmaxf(rm, __shfl_xor(rm, 4));
        rm = fmaxf(rm, __shfl_xor(rm, 8));
        float mn = fmaxf(mrow[i][r], rm);
        float a = __expf(mrow[i][r] - mn);
        alpha[i][r] = a;
        mrow[i][r] = mn;
        float ps = 0.f;
#pragma unroll
        for (int j = 0; j < 8; ++j) {
          float p = __expf(sacc[i][j][r] - mn);
          sacc[i][j][r] = p;
          ps += p;
        }
        ps += __shfl_xor(ps, 1);
        ps += __shfl_xor(ps, 2);
        ps += __shfl_xor(ps, 4);
        ps += __shfl_xor(ps, 8);
        lsum[i][r] = lsum[i][r] * a + ps;
      }

    // P -> LDS (C-layout scatter, bf16), rescale O
#pragma unroll
    for (int i = 0; i < 2; ++i)
#pragma unroll
      for (int j = 0; j < 8; ++j)
#pragma unroll
        for (int r = 0; r < 4; ++r)
          Ps[(wave * 32 + i * 16 + lquad * 4 + r) * 128 + j * 16 + lrow] =
              f2bf(sacc[i][j][r]);
#pragma unroll
    for (int i = 0; i < 2; ++i)
#pragma unroll
      for (int jn = 0; jn < 4; ++jn)
#pragma unroll
        for (int r = 0; r < 4; ++r) oacc[i][jn][r] *= alpha[i][r];
    __syncthreads();

    // O += P @ V   (contraction over 128 keys, V^T gives contiguous B-frags)
#pragma unroll
    for (int kk = 0; kk < 4; ++kk) {
      bf16x8 pf[2];
#pragma unroll
      for (int i = 0; i < 2; ++i)
        pf[i] = *(const bf16x8*)(Ps + (wave * 32 + i * 16 + lrow) * 128 +
                                 kk * 32 + lquad * 8);
#pragma unroll
      for (int jn = 0; jn < 4; ++jn) {
        bf16x8 vf = *(const bf16x8*)(Vs + (jn * 16 + lrow) * 128 + kk * 32 + lquad * 8);
        oacc[0][jn] = mfma16(pf[0], vf, oacc[0][jn]);
        oacc[1][jn] = mfma16(pf[1], vf, oacc[1][jn]);
      }
    }
    __syncthreads();
  }

  const int b = bh >> 4, h = bh & 15;
#pragma unroll
  for (int i = 0; i < 2; ++i)
#pragma unroll
    for (int r = 0; r < 4; ++r) {
      float inv = 1.f / lsum[i][r];
      int s = qb * 128 + wave * 32 + i * 16 + lquad * 4 + r;
      size_t base = ((size_t)(b * 2048 + s)) * 1024 + h * 64;
#pragma unroll
      for (int jn = 0; jn < 4; ++jn)
        ctx[base + jn * 16 + lrow] = f2bf(oacc[i][jn][r] * inv);
    }
}

// ---------------- LayerNorm over D=1024 with fused residual add ----------------
__global__ __launch_bounds__(256)
void ln_kernel(const float* __restrict__ x1, const float* __restrict__ x2,
               const float* __restrict__ g, const float* __restrict__ bb,
               float* __restrict__ outf, u16* __restrict__ outb) {
  const int t = blockIdx.x;
  const int tid = threadIdx.x;
  const int lane = tid & 63, wave = tid >> 6;
  const size_t base = (size_t)t * 1024;
  float v[4];
  float s = 0.f, s2 = 0.f;
#pragma unroll
  for (int e = 0; e < 4; ++e) {
    int i = tid + e * 256;
    float x = x1[base + i] + x2[base + i];
    v[e] = x;
    s += x;
    s2 += x * x;
  }
#pragma unroll
  for (int d = 1; d < 64; d <<= 1) {
    s += __shfl_xor(s, d);
    s2 += __shfl_xor(s2, d);
  }
  __shared__ float red[8];
  if (lane == 0) { red[wave] = s; red[4 + wave] = s2; }
  __syncthreads();
  s = red[0] + red[1] + red[2] + red[3];
  s2 = red[4] + red[5] + red[6] + red[7];
  float mean = s * (1.f / 1024.f);
  float var = s2 * (1.f / 1024.f) - mean * mean;
  float rstd = rsqrtf(var + 1e-5f);
#pragma unroll
  for (int e = 0; e < 4; ++e) {
    int i = tid + e * 256;
    float y = (v[e] - mean) * rstd * g[i] + bb[i];
    outf[base + i] = y;
    if (outb) outb[base + i] = f2bf(y);
  }
}

// ---------------- launch ----------------
extern "C" void kernel_launch(void* const* d_in, const int* in_sizes, int n_in,
                              void* d_out, int out_size, void* d_ws, size_t ws_size,
                              hipStream_t stream) {
  const float* src    = (const float*)d_in[0];
  const float* qkv_w  = (const float*)d_in[1];
  const float* qkv_b  = (const float*)d_in[2];
  const float* out_w  = (const float*)d_in[3];
  const float* out_b  = (const float*)d_in[4];
  const float* ffn_w1 = (const float*)d_in[5];
  const float* ffn_b1 = (const float*)d_in[6];
  const float* ffn_w2 = (const float*)d_in[7];
  const float* ffn_b2 = (const float*)d_in[8];
  const float* ln1_g  = (const float*)d_in[9];
  const float* ln1_b  = (const float*)d_in[10];
  const float* ln2_g  = (const float*)d_in[11];
  const float* ln2_b  = (const float*)d_in[12];

  char* ws = (char*)d_ws;
  size_t off = 0;
  auto alloc = [&](size_t bytes) -> void* {
    void* p = ws + off;
    off += (bytes + 255) & ~(size_t)255;
    return p;
  };
  // ~160 MB total workspace
  u16* wqkv = (u16*)alloc(3072ull * 1024 * 2);
  u16* wout = (u16*)alloc(1024ull * 1024 * 2);
  u16* wf1  = (u16*)alloc(4096ull * 1024 * 2);
  u16* wf2  = (u16*)alloc(1024ull * 4096 * 2);
  u16* srcb = (u16*)alloc(4096ull * 1024 * 2);
  u16* qb_  = (u16*)alloc(32ull * 2048 * 64 * 2);
  u16* kb_  = (u16*)alloc(32ull * 2048 * 64 * 2);
  u16* vtb  = (u16*)alloc(32ull * 64 * 2048 * 2);
  u16* ctxb = (u16*)alloc(4096ull * 1024 * 2);
  float* mha  = (float*)alloc(4096ull * 1024 * 4);
  float* aggf = (float*)alloc(4096ull * 1024 * 4);
  u16* aggb = (u16*)alloc(4096ull * 1024 * 2);
  u16* hb   = (u16*)alloc(4096ull * 4096 * 2);
  float* ffnf = (float*)alloc(4096ull * 1024 * 4);

  // fp32 -> bf16 converts (weights re-converted every call; harness re-poisons ws)
  cvt_bf16<<<3072 * 1024 / 1024, 256, 0, stream>>>(qkv_w, wqkv);
  cvt_bf16<<<1024 * 1024 / 1024, 256, 0, stream>>>(out_w, wout);
  cvt_bf16<<<4096 * 1024 / 1024, 256, 0, stream>>>(ffn_w1, wf1);
  cvt_bf16<<<4096 * 1024 / 1024, 256, 0, stream>>>(ffn_w2, wf2);
  cvt_bf16<<<4096 * 1024 / 1024, 256, 0, stream>>>(src, srcb);

  // QKV projection + head scatter (q scaled, v transposed)
  gemm_bt<2><<<dim3(32, 24), 256, 0, stream>>>(srcb, wqkv, qkv_b, nullptr, nullptr,
                                               qb_, kb_, vtb, 4096, 3072, 1024);
  // flash attention -> ctx [B,S,D] bf16
  attn_kernel<<<dim3(16, 32), 256, 0, stream>>>(qb_, kb_, vtb, ctxb);
  // output projection -> mha fp32
  gemm_bt<0><<<dim3(32, 8), 256, 0, stream>>>(ctxb, wout, out_b, mha, nullptr,
                                              nullptr, nullptr, nullptr, 4096, 1024, 1024);
  // LN1(src + mha) -> agg fp32 + bf16
  ln_kernel<<<4096, 256, 0, stream>>>(src, mha, ln1_g, ln1_b, aggf, aggb);
  // FFN1 + ReLU -> h bf16
  gemm_bt<1><<<dim3(32, 32), 256, 0, stream>>>(aggb, wf1, ffn_b1, nullptr, hb,
                                               nullptr, nullptr, nullptr, 4096, 4096, 1024);
  // FFN2 -> ffn fp32
  gemm_bt<0><<<dim3(32, 8), 256, 0, stream>>>(hb, wf2, ffn_b2, ffnf, nullptr,
                                              nullptr, nullptr, nullptr, 4096, 1024, 4096);
  // LN2(agg + ffn) -> d_out fp32
  ln_kernel<<<4096, 256, 0, stream>>>(aggf, ffnf, ln2_g, ln2_b, (float*)d_out, nullptr);
}